// Round 8
// baseline (322.508 us; speedup 1.0000x reference)
//
#include <hip/hip_runtime.h>
#include <stdint.h>

#define N_NODES 500000
#define K_NB 16
#define F_IN 7
#define F_HID 40
#define F_OUT 3
#define NODE_FLOATS (K_NB * F_IN)     // 112 floats per node
#define NPW 16                        // nodes per wave-tile
#define WPB 4                         // waves per block
#define TILE_FLOATS (NPW * NODE_FLOATS)  // 1792 floats = 7168 B
#define NT (N_NODES / NPW)            // 31250 tiles (500000 % 16 == 0)
#define GRID_BLOCKS 512               // 2 blocks/CU (LDS-limited), persistent
#define NW (GRID_BLOCKS * WPB)        // 2048 wave streams

typedef float v2f __attribute__((ext_vector_type(2)));

typedef __attribute__((address_space(3))) void lds_void_t;
typedef __attribute__((address_space(1))) const void glb_void_t;
typedef __attribute__((address_space(4))) const float kfloat;  // -> s_load path

// R7 falsified the LDS-pipe theory (removed 95% of LDS reads, neutral).
// Surviving evidence: R6 per-rep HBM BW only 1.48 TB/s (18%) and R5's
// L3-warm relaunch still 71.6us -> the binder is the un-pipelined
// stage -> vmcnt(0) -> compute structure + block churn (31 short blocks/CU):
// every wave eats full HBM latency per 7KB tile and the VM queue drains.
// Fix (the documented m97->AITER path): persistent waves, double-buffered
// global_load_lds, s_waitcnt vmcnt(7) so the queue NEVER drains.
__global__ void prep_kernel(const float* __restrict__ W1,
                            const float* __restrict__ b1,
                            const float* __restrict__ W2,
                            float* __restrict__ ws)
{
    const int t = threadIdx.x;
    if (t < F_HID) {
        float* p = ws + t * 8;   // {W1[0..6][h], b1[h]}
        #pragma unroll
        for (int i = 0; i < F_IN; ++i) p[i] = W1[i * F_HID + t];
        p[7] = b1[t];
    } else if (t < 2 * F_HID) {
        const int h = t - F_HID;
        float* p = ws + F_HID * 8 + h * 4;  // {W2[h][0..2], 0}
        p[0] = W2[h * F_OUT + 0];
        p[1] = W2[h * F_OUT + 1];
        p[2] = W2[h * F_OUT + 2];
        p[3] = 0.0f;
    }
}

__global__ __launch_bounds__(256) void aggre_kernel(
    const float* __restrict__ mailbox,
    const float* __restrict__ wtab,   // [40][8]
    const float* __restrict__ w2tab,  // [40][4]
    const float* __restrict__ b2,
    float* __restrict__ out)
{
    // per wave: two 7168B staging buffers (double buffer). 4*2*7168 = 57344 B.
    __shared__ __align__(16) float tile[WPB][2][TILE_FLOATS];

    const int t  = threadIdx.x;
    const int wave = t >> 6;
    const int lane = t & 63;
    const int wid = blockIdx.x * WPB + wave;   // 0..2047 persistent wave stream

    const kfloat* wt  = (const kfloat*)(uintptr_t)wtab;
    const kfloat* w2t = (const kfloat*)(uintptr_t)w2tab;
    const float bo0 = b2[0], bo1 = b2[1], bo2 = b2[2];

    const int nloc = lane >> 2;
    const int r = lane & 3;
    const int mbase = nloc * NODE_FLOATS + r * 28;

    // ---- prologue: stage first tile into buf 0 ----
    long tt = wid;                       // first tile (wid < 2048 < NT always)
    {
        const float* g0 = mailbox + (size_t)tt * TILE_FLOATS;
        #pragma unroll
        for (int j = 0; j < 7; ++j) {
            __builtin_amdgcn_global_load_lds(
                (glb_void_t*)(g0 + (size_t)(j * 64 + lane) * 4),
                (lds_void_t*)&tile[wave][0][j * 256], 16, 0, 0);
        }
    }
    int parity = 0;

    while (true) {
        const long tn = tt + NW;
        if (tn < NT) {
            // guard: all ds_reads of the buffer we are about to overwrite
            // retired (previous compute) -- lgkmcnt(0), vmcnt untouched.
            __builtin_amdgcn_s_waitcnt(0xC07F);
            const float* g = mailbox + (size_t)tn * TILE_FLOATS;
            #pragma unroll
            for (int j = 0; j < 7; ++j) {
                __builtin_amdgcn_global_load_lds(
                    (glb_void_t*)(g + (size_t)(j * 64 + lane) * 4),
                    (lds_void_t*)&tile[wave][parity ^ 1][j * 256], 16, 0, 0);
            }
            // wait ONLY for tile tt's 7 loads; tn's 7 stay in flight.
            __builtin_amdgcn_s_waitcnt(0x0F77);   // vmcnt(7)
        } else {
            __builtin_amdgcn_s_waitcnt(0x0F70);   // vmcnt(0) last tile
        }

        // ---- compute tile tt from tile[wave][parity] ----
        const float* tb = &tile[wave][parity][0];
        v2f mA[F_IN], mB[F_IN];
        #pragma unroll
        for (int j = 0; j < F_IN; ++j) {
            v2f a, b;
            a.x = tb[mbase + j];          // k = 4r      (pairs 7 dwords apart
            a.y = tb[mbase + 7 + j];      // k = 4r+1     -> ds_read2_b32)
            b.x = tb[mbase + 14 + j];     // k = 4r+2
            b.y = tb[mbase + 21 + j];     // k = 4r+3
            mA[j] = a;
            mB[j] = b;
        }

        const v2f zero = {0.0f, 0.0f};
        v2f a0 = zero, a1 = zero, a2 = zero;

        #pragma unroll 4
        for (int h = 0; h < F_HID; ++h) {
            const float w0 = wt[h * 8 + 0], w1 = wt[h * 8 + 1];
            const float w2 = wt[h * 8 + 2], w3 = wt[h * 8 + 3];
            const float w4 = wt[h * 8 + 4], w5 = wt[h * 8 + 5];
            const float w6 = wt[h * 8 + 6], bb = wt[h * 8 + 7];
            const v2f wv0 = {w0, w0}, wv1 = {w1, w1}, wv2 = {w2, w2};
            const v2f wv3 = {w3, w3}, wv4 = {w4, w4}, wv5 = {w5, w5};
            const v2f wv6 = {w6, w6}, bbv = {bb, bb};

            v2f accA = mA[0] * wv0;
            v2f accB = mB[0] * wv0;
            accA = __builtin_elementwise_fma(mA[1], wv1, accA);
            accB = __builtin_elementwise_fma(mB[1], wv1, accB);
            accA = __builtin_elementwise_fma(mA[2], wv2, accA);
            accB = __builtin_elementwise_fma(mB[2], wv2, accB);
            accA = __builtin_elementwise_fma(mA[3], wv3, accA);
            accB = __builtin_elementwise_fma(mB[3], wv3, accB);
            accA = __builtin_elementwise_fma(mA[4], wv4, accA);
            accB = __builtin_elementwise_fma(mB[4], wv4, accB);
            accA = __builtin_elementwise_fma(mA[5], wv5, accA);
            accB = __builtin_elementwise_fma(mB[5], wv5, accB);
            accA = __builtin_elementwise_fma(mA[6], wv6, accA);
            accB = __builtin_elementwise_fma(mB[6], wv6, accB);

            accA = __builtin_elementwise_max(accA + bbv, zero);
            accB = __builtin_elementwise_max(accB + bbv, zero);
            const v2f sh = accA + accB;

            const float u0 = w2t[h * 4 + 0];
            const float u1 = w2t[h * 4 + 1];
            const float u2 = w2t[h * 4 + 2];
            const v2f uv0 = {u0, u0}, uv1 = {u1, u1}, uv2 = {u2, u2};
            a0 = __builtin_elementwise_fma(sh, uv0, a0);
            a1 = __builtin_elementwise_fma(sh, uv1, a1);
            a2 = __builtin_elementwise_fma(sh, uv2, a2);
        }

        float s0 = a0.x + a0.y;
        float s1 = a1.x + a1.y;
        float s2 = a2.x + a2.y;
        s0 += __shfl_xor(s0, 1); s0 += __shfl_xor(s0, 2);
        s1 += __shfl_xor(s1, 1); s1 += __shfl_xor(s1, 2);
        s2 += __shfl_xor(s2, 1); s2 += __shfl_xor(s2, 2);

        if (r < F_OUT) {
            const float val = (r == 0) ? s0 : ((r == 1) ? s1 : s2);
            out[((size_t)tt * NPW + nloc) * F_OUT + r] =
                fmaf(val, 1.0f / (float)K_NB, b2[r]);
        }

        if (tn >= NT) break;
        tt = tn;
        parity ^= 1;
    }
    (void)bo0; (void)bo1; (void)bo2;
}

extern "C" void kernel_launch(void* const* d_in, const int* in_sizes, int n_in,
                              void* d_out, int out_size, void* d_ws, size_t ws_size,
                              hipStream_t stream) {
    const float* mailbox = (const float*)d_in[0];
    const float* W1      = (const float*)d_in[1];
    const float* b1      = (const float*)d_in[2];
    const float* W2      = (const float*)d_in[3];
    const float* b2      = (const float*)d_in[4];
    float* ws  = (float*)d_ws;
    float* out = (float*)d_out;

    prep_kernel<<<1, 128, 0, stream>>>(W1, b1, W2, ws);

    const float* wtab  = ws;             // 40*8 floats
    const float* w2tab = ws + F_HID * 8; // 40*4 floats
    aggre_kernel<<<GRID_BLOCKS, 256, 0, stream>>>(mailbox, wtab, w2tab, b2, out);
}